// Round 1
// baseline (867.662 us; speedup 1.0000x reference)
//
#include <hip/hip_runtime.h>
#include <hip/hip_bf16.h>

// RNN_41807211659578: T=48 persistent GRU rollout, bf16 MFMA.
// 184 blocks x 512 thr; block owns 32 rows (one agent, 32 consecutive batch).
// Weights converted to bf16 [j][k] (B-fragment layout) in d_ws by prep kernel.

typedef unsigned short u16;
typedef unsigned int u32;
typedef __attribute__((ext_vector_type(8))) short bf16x8;
typedef __attribute__((ext_vector_type(4))) float f32x4;

#define MFMA_B16(acc, a, b) (acc) = __builtin_amdgcn_mfma_f32_16x16x32_bf16((a), (b), (acc), 0, 0, 0)

__device__ __forceinline__ float b2f(u16 u) {
  union { u32 i; float f; } v; v.i = ((u32)u) << 16; return v.f;
}
__device__ __forceinline__ u16 f2b(float f) {
  union { u32 i; float f; } v; v.f = f;
  u32 r = (v.i + 0x7fffu + ((v.i >> 16) & 1u)) >> 16;
  return (u16)r;
}
__device__ __forceinline__ bf16x8 ldb(const u16* p) { return *(const bf16x8*)p; }

__device__ __forceinline__ float sigf(float x) {
  return __builtin_amdgcn_rcpf(1.f + __expf(-x));
}
__device__ __forceinline__ float tanh_fast(float x) {
  return 1.f - 2.f * __builtin_amdgcn_rcpf(1.f + __expf(2.f * x));
}

// ---- workspace layout (E* are ushort offsets in the bf16 region) ----
constexpr int E0 = 2 * 384 * 352;   // W0cat [g][384][352] = [Wih0(0:94)|0,0|Wih0(94:222)|Whh0]
constexpr int E1 = E0 + 2 * 384 * 256; // W1cat [g][384][256] = [Wih1|Whh1]
constexpr int E2 = E1 + 2 * 128 * 128; // Wn0 = Whh0 n-rows
constexpr int E3 = E2 + 2 * 128 * 128; // Wn1 = Whh1 n-rows
constexpr int E4 = E3 + 2 * 128 * 128; // W1 (MLP) bf16
constexpr int E5 = E4 + 2 * 128 * 128; // W2 (MLP) bf16
constexpr int NBIAS = 2048;            // fp32 biases at wsf[4..]
constexpr int TOTAL = E5 + NBIAS + 4;  // + acc zeroing (wsf[0..3])
constexpr int WB_OFF = 8192;           // ushort offset of bf16 region (byte 16384)

__global__ void prep_kernel(const float* __restrict__ Wih0, const float* __restrict__ Whh0,
                            const float* __restrict__ bih0, const float* __restrict__ bhh0,
                            const float* __restrict__ Wih1, const float* __restrict__ Whh1,
                            const float* __restrict__ bih1, const float* __restrict__ bhh1,
                            const float* __restrict__ W1, const float* __restrict__ W2,
                            u16* __restrict__ wb, float* __restrict__ wsf) {
  for (int idx = blockIdx.x * blockDim.x + threadIdx.x; idx < TOTAL;
       idx += gridDim.x * blockDim.x) {
    if (idx < E0) {
      int g = idx / 135168;
      int r = idx - g * 135168;
      int j = r / 352;
      int k = r - j * 352;
      const float* wi = Wih0 + (g * 384 + j) * 222;
      float v;
      if (k < 94) v = wi[k];
      else if (k < 96) v = 0.f;
      else if (k < 224) v = wi[k - 2];          // enc col 94+(k-96)
      else v = Whh0[(g * 384 + j) * 128 + (k - 224)];
      wb[idx] = f2b(v);
    } else if (idx < E1) {
      int q = idx - E0;
      int g = q / 98304;
      int r = q - g * 98304;
      int j = r >> 8;
      int k = r & 255;
      float v = (k < 128) ? Wih1[(g * 384 + j) * 128 + k]
                          : Whh1[(g * 384 + j) * 128 + (k - 128)];
      wb[idx] = f2b(v);
    } else if (idx < E2) {
      int q = idx - E1; int g = q >> 14; int r = q & 16383; int j = r >> 7; int k = r & 127;
      wb[idx] = f2b(Whh0[(g * 384 + 256 + j) * 128 + k]);
    } else if (idx < E3) {
      int q = idx - E2; int g = q >> 14; int r = q & 16383; int j = r >> 7; int k = r & 127;
      wb[idx] = f2b(Whh1[(g * 384 + 256 + j) * 128 + k]);
    } else if (idx < E4) {
      int q = idx - E3; int g = q >> 14; int r = q & 16383; int j = r >> 7; int k = r & 127;
      wb[idx] = f2b(W1[(g * 128 + j) * 128 + k]);
    } else if (idx < E5) {
      int q = idx - E4; int g = q >> 14; int r = q & 16383; int j = r >> 7; int k = r & 127;
      wb[idx] = f2b(W2[(g * 128 + j) * 128 + k]);
    } else if (idx < E5 + NBIAS) {
      int q = idx - E5;
      float v;
      if (q < 512)       { int g = q >> 8, j = q & 255;              v = bih0[g*384 + j] + bhh0[g*384 + j]; }
      else if (q < 768)  { int p = q - 512;  int g = p >> 7, j = p & 127; v = bih0[g*384 + 256 + j]; }
      else if (q < 1024) { int p = q - 768;  int g = p >> 7, j = p & 127; v = bhh0[g*384 + 256 + j]; }
      else if (q < 1536) { int p = q - 1024; int g = p >> 8, j = p & 255; v = bih1[g*384 + j] + bhh1[g*384 + j]; }
      else if (q < 1792) { int p = q - 1536; int g = p >> 7, j = p & 127; v = bih1[g*384 + 256 + j]; }
      else               { int p = q - 1792; int g = p >> 7, j = p & 127; v = bhh1[g*384 + 256 + j]; }
      wsf[4 + q] = v;
    } else {
      wsf[idx - (E5 + NBIAS)] = 0.f; // zero accumulators wsf[0..3]
    }
  }
}

// ---- MFMA segment helpers ----
// A-frag: lane holds A[m=lane&15][k=(lane>>4)*8 + j]; B-frag: lane holds B^T-style
// W[n=lane&15][k=(lane>>4)*8 + j] (W stored [j][k], k contiguous). D: row=(lane>>4)*4+i, col=lane&15.

template<int KT, int SA>
__device__ __forceinline__ void seg_one(f32x4 (&acc)[2], const u16* __restrict__ aB,
                                        const u16* __restrict__ wB) {
#pragma unroll
  for (int kt = 0; kt < KT; ++kt) {
    bf16x8 a0 = ldb(aB + kt * 32);
    bf16x8 a1 = ldb(aB + 16 * SA + kt * 32);
    bf16x8 b = ldb(wB + kt * 32);
    MFMA_B16(acc[0], a0, b);
    MFMA_B16(acc[1], a1, b);
  }
}

template<int KT, int SA, int WKW>
__device__ __forceinline__ void seg_rzn(f32x4 (&aR)[2], f32x4 (&aZ)[2], f32x4 (&aN)[2],
                                        const u16* __restrict__ aB, const u16* __restrict__ wR) {
#pragma unroll
  for (int kt = 0; kt < KT; ++kt) {
    bf16x8 a0 = ldb(aB + kt * 32);
    bf16x8 a1 = ldb(aB + 16 * SA + kt * 32);
    bf16x8 b0 = ldb(wR + kt * 32);
    bf16x8 b1 = ldb(wR + 128 * WKW + kt * 32);
    bf16x8 b2 = ldb(wR + 256 * WKW + kt * 32);
    MFMA_B16(aR[0], a0, b0); MFMA_B16(aR[1], a1, b0);
    MFMA_B16(aZ[0], a0, b1); MFMA_B16(aZ[1], a1, b1);
    MFMA_B16(aN[0], a0, b2); MFMA_B16(aN[1], a1, b2);
  }
}

__device__ __forceinline__ void gru_combine(u16 (*hb)[136], int jh, int kq,
                                            f32x4 (&aR)[2], f32x4 (&aZ)[2],
                                            f32x4 (&aN)[2], f32x4 (&aG)[2],
                                            float bR, float bZ, float bIN, float bHN,
                                            u16 (&hn)[2][4]) {
#pragma unroll
  for (int mt = 0; mt < 2; ++mt) {
#pragma unroll
    for (int i = 0; i < 4; ++i) {
      int row = mt * 16 + kq * 4 + i;
      float r = sigf(aR[mt][i] + bR);
      float z = sigf(aZ[mt][i] + bZ);
      float gn = aG[mt][i];
      // true input to tanh: (gi_n + bIN) + r*(gh_n + bHN); acc aN = gi_n+gh_n, aG = gh_n
      float n = tanh_fast(aN[mt][i] + bIN + (r - 1.f) * gn + r * bHN);
      float hold = b2f(hb[row][jh]);
      hn[mt][i] = f2b((1.f - z) * n + z * hold);
    }
  }
}

__global__ __launch_bounds__(512)
void rnn_kernel(const float* __restrict__ states,
                const u16* __restrict__ wb,
                float* __restrict__ wsf,
                const float* __restrict__ b1g,
                const float* __restrict__ b2g,
                const float* __restrict__ Wmg,
                const float* __restrict__ bmg) {
  const int blk = blockIdx.x;
  const int g = (blk < 96) ? 0 : 1;
  const int r0 = (g == 0) ? (blk * 32) : ((blk - 96) * 32);
  const int aAg = (g == 0 ? 0 : 12) + (r0 >> 8); // absolute agent index (blocks never straddle agents)
  const int b0 = r0 & 255;

  const int tid = threadIdx.x;
  const int wid = tid >> 6;
  const int ln = tid & 63;
  const int j_in = ln & 15;
  const int kq = ln >> 4;
  const int jh = wid * 16 + j_in; // hidden column owned by this lane (0..127)

  __shared__ __align__(16) u16 h0b[32][136];
  __shared__ __align__(16) u16 h1b[32][136];
  __shared__ __align__(16) u16 yv[32][104];  // [vel(2)|y(92)|pad]
  __shared__ __align__(16) u16 dbf[32][136];
  __shared__ float dmv[32][2];
  __shared__ float red[32][3];

  const u16* W0c  = wb + g * 135168;
  const u16* W1c  = wb + E0 + g * 98304;
  const u16* Wn0w = wb + E1 + g * 16384;
  const u16* Wn1w = wb + E2 + g * 16384;
  const u16* Wm1w = wb + E3 + g * 16384;
  const u16* Wm2w = wb + E4 + g * 16384;

  const float* bs0  = wsf + 4 + g * 256;
  const float* bin0 = wsf + 516 + g * 128;
  const float* bhn0 = wsf + 772 + g * 128;
  const float* bs1  = wsf + 1028 + g * 256;
  const float* bin1 = wsf + 1540 + g * 128;
  const float* bhn1 = wsf + 1796 + g * 128;

  const u16* aY  = &yv[j_in][kq * 8];
  const u16* aH0 = &h0b[j_in][kq * 8];
  const u16* aH1 = &h1b[j_in][kq * 8];
  const u16* aD  = &dbf[j_in][kq * 8];
  const u16* w0l  = W0c + jh * 352 + kq * 8;
  const u16* w1l  = W1c + jh * 256 + kq * 8;
  const u16* wn0l = Wn0w + jh * 128 + kq * 8;
  const u16* wn1l = Wn1w + jh * 128 + kq * 8;
  const u16* wm1l = Wm1w + jh * 128 + kq * 8;
  const u16* wm2l = Wm2w + jh * 128 + kq * 8;

  const float bR0 = bs0[jh], bZ0 = bs0[128 + jh], bIN0 = bin0[jh], bHN0 = bhn0[jh];
  const float bR1 = bs1[jh], bZ1 = bs1[128 + jh], bIN1 = bin1[jh], bHN1 = bhn1[jh];
  const float b1v = b1g[g * 128 + jh];
  const float b2v = b2g[g * 128 + jh];

  for (int i = tid; i < 32 * 128; i += 512) {
    h0b[i >> 7][i & 127] = 0;
    h1b[i >> 7][i & 127] = 0;
  }

  float accL = 0.f, accEp = 0.f, accEv = 0.f;

  for (int t = 0; t < 48; ++t) {
    __syncthreads(); // A: yv(t-1) fully consumed, h1b(t-1) written
    // ---- stage yv = [vel | y_t | 0] in bf16 ----
    for (int idx = tid; idx < 32 * 96; idx += 512) {
      int i = idx / 96;
      int k = idx - i * 96;
      const float* srow = states + ((size_t)(t * 256 + b0 + i)) * 92;
      float v;
      if (k < 2) v = srow[aAg * 4 + 2 + k];
      else if (k < 94) v = srow[k - 2];
      else v = 0.f;
      yv[i][k] = f2b(v);
    }
    __syncthreads(); // B

    // ---- MLP layer 1: d1 = relu(h1 @ W1^T + b1) ----
    {
      f32x4 acc[2] = {{0.f,0.f,0.f,0.f}, {0.f,0.f,0.f,0.f}};
      seg_one<4, 136>(acc, aH1, wm1l);
#pragma unroll
      for (int i = 0; i < 4; ++i) {
        dbf[kq * 4 + i][jh]      = f2b(fmaxf(acc[0][i] + b1v, 0.f));
        dbf[16 + kq * 4 + i][jh] = f2b(fmaxf(acc[1][i] + b1v, 0.f));
      }
    }
    __syncthreads(); // C
    // ---- MLP layer 2: d2 = relu(d1 @ W2^T + b2) (in-place in dbf) ----
    {
      f32x4 acc[2] = {{0.f,0.f,0.f,0.f}, {0.f,0.f,0.f,0.f}};
      seg_one<4, 136>(acc, aD, wm2l);
      __syncthreads(); // D: all reads of d1 done
#pragma unroll
      for (int i = 0; i < 4; ++i) {
        dbf[kq * 4 + i][jh]      = f2b(fmaxf(acc[0][i] + b2v, 0.f));
        dbf[16 + kq * 4 + i][jh] = f2b(fmaxf(acc[1][i] + b2v, 0.f));
      }
    }
    __syncthreads(); // E
    // ---- dm = d2 @ Wm^T + bm (2 cols, vector) ----
    if (tid < 64) {
      int row = tid >> 1, c = tid & 1;
      const float* wmr = Wmg + (g * 2 + c) * 128;
      float s = bmg[g * 2 + c];
      for (int k = 0; k < 128; ++k) s += wmr[k] * b2f(dbf[row][k]);
      dmv[row][c] = s;
    }
    __syncthreads(); // F
    // ---- per-row error terms ----
    if (tid < 32) {
      const float* srow = states + ((size_t)(t * 256 + b0 + tid)) * 92 + aAg * 4;
      const float* srn  = states + ((size_t)((t + 1) * 256 + b0 + tid)) * 92 + aAg * 4;
      float dx = dmv[tid][0] - srn[2];
      float dy = dmv[tid][1] - srn[3];
      float e = sqrtf(dx * dx + dy * dy);
      accL += e;
      if (t >= 12) {
        accEv += e;
        float ex = srow[0] + 0.1f * srow[2] - srn[0];
        float ey = srow[1] + 0.1f * srow[3] - srn[1];
        accEp += sqrtf(ex * ex + ey * ey);
      }
    }
    // ---- GRU layer 0: A = [vel|y|h1 | h0] vs W0cat; extra aG = h0 @ Whh0_n ----
    {
      f32x4 aR[2] = {{0.f,0.f,0.f,0.f},{0.f,0.f,0.f,0.f}};
      f32x4 aZ[2] = {{0.f,0.f,0.f,0.f},{0.f,0.f,0.f,0.f}};
      f32x4 aN[2] = {{0.f,0.f,0.f,0.f},{0.f,0.f,0.f,0.f}};
      f32x4 aG[2] = {{0.f,0.f,0.f,0.f},{0.f,0.f,0.f,0.f}};
      seg_rzn<3, 104, 352>(aR, aZ, aN, aY, w0l);         // K 0..95  (vel+y)
      seg_rzn<4, 136, 352>(aR, aZ, aN, aH1, w0l + 96);   // K 96..223 (h1)
      seg_rzn<4, 136, 352>(aR, aZ, aN, aH0, w0l + 224);  // K 224..351 (h0, gh part)
      seg_one<4, 136>(aG, aH0, wn0l);                    // gh_n only
      u16 hn[2][4];
      gru_combine(h0b, jh, kq, aR, aZ, aN, aG, bR0, bZ0, bIN0, bHN0, hn);
      __syncthreads(); // G: all reads of h0b/h1b/yv done
#pragma unroll
      for (int mt = 0; mt < 2; ++mt)
#pragma unroll
        for (int i = 0; i < 4; ++i)
          h0b[mt * 16 + kq * 4 + i][jh] = hn[mt][i];
    }
    __syncthreads(); // H: h0b now = h0_new
    // ---- GRU layer 1: A = [h0_new | h1_old] vs W1cat; aG = h1_old @ Whh1_n ----
    {
      f32x4 aR[2] = {{0.f,0.f,0.f,0.f},{0.f,0.f,0.f,0.f}};
      f32x4 aZ[2] = {{0.f,0.f,0.f,0.f},{0.f,0.f,0.f,0.f}};
      f32x4 aN[2] = {{0.f,0.f,0.f,0.f},{0.f,0.f,0.f,0.f}};
      f32x4 aG[2] = {{0.f,0.f,0.f,0.f},{0.f,0.f,0.f,0.f}};
      seg_rzn<4, 136, 256>(aR, aZ, aN, aH0, w1l);        // K 0..127 (h0_new, gi)
      seg_rzn<4, 136, 256>(aR, aZ, aN, aH1, w1l + 128);  // K 128..255 (h1_old, gh)
      seg_one<4, 136>(aG, aH1, wn1l);
      u16 hn[2][4];
      gru_combine(h1b, jh, kq, aR, aZ, aN, aG, bR1, bZ1, bIN1, bHN1, hn);
      __syncthreads(); // I: all reads of h1b done
#pragma unroll
      for (int mt = 0; mt < 2; ++mt)
#pragma unroll
        for (int i = 0; i < 4; ++i)
          h1b[mt * 16 + kq * 4 + i][jh] = hn[mt][i];
    }
  }

  if (tid < 32) { red[tid][0] = accL; red[tid][1] = accEp; red[tid][2] = accEv; }
  __syncthreads();
  if (tid < 3) {
    float s = 0.f;
    for (int i = 0; i < 32; ++i) s += red[i][tid];
    atomicAdd(&wsf[tid], s);
  }
}

__global__ void fin_kernel(const float* __restrict__ wacc, float* __restrict__ out) {
  if (threadIdx.x == 0 && blockIdx.x == 0) {
    out[0] = wacc[0] / 1104.f; // / (T*NA)
    out[1] = wacc[1] / 828.f;  // / ((T-BURN)*NA)
    out[2] = wacc[2] / 828.f;
  }
}

extern "C" void kernel_launch(void* const* d_in, const int* in_sizes, int n_in,
                              void* d_out, int out_size, void* d_ws, size_t ws_size,
                              hipStream_t stream) {
  const float* states = (const float*)d_in[0];
  const float* Wih0 = (const float*)d_in[1];
  const float* Whh0 = (const float*)d_in[2];
  const float* bih0 = (const float*)d_in[3];
  const float* bhh0 = (const float*)d_in[4];
  const float* Wih1 = (const float*)d_in[5];
  const float* Whh1 = (const float*)d_in[6];
  const float* bih1 = (const float*)d_in[7];
  const float* bhh1 = (const float*)d_in[8];
  const float* W1   = (const float*)d_in[9];
  const float* b1   = (const float*)d_in[10];
  const float* W2   = (const float*)d_in[11];
  const float* b2   = (const float*)d_in[12];
  const float* Wm   = (const float*)d_in[13];
  const float* bm   = (const float*)d_in[14];

  float* wsf = (float*)d_ws;
  u16* wb = (u16*)d_ws + WB_OFF;

  int prep_blocks = (TOTAL + 255) / 256;
  prep_kernel<<<prep_blocks, 256, 0, stream>>>(Wih0, Whh0, bih0, bhh0,
                                               Wih1, Whh1, bih1, bhh1,
                                               W1, W2, wb, wsf);
  rnn_kernel<<<184, 512, 0, stream>>>(states, wb, wsf, b1, b2, Wm, bm);
  fin_kernel<<<1, 64, 0, stream>>>(wsf, (float*)d_out);
}

// Round 2
// 429.965 us; speedup vs baseline: 2.0180x; 2.0180x over previous
//
#include <hip/hip_runtime.h>
#include <hip/hip_bf16.h>

// RNN_41807211659578 R2: register-resident fp8 weights, persistent 48-step GRU.
// 184 blocks x 512 thr; block owns 32 rows. Weights fp8 e4m3 in VGPRs (146/lane),
// activations fp8 in LDS (A-frags), bf16 shadow for recurrent carry.

typedef unsigned short u16;
typedef unsigned int u32;
typedef unsigned char u8;
typedef long i64;
typedef __attribute__((ext_vector_type(4))) float f32x4;

#define MFMA_F8(acc, a, b) (acc) = __builtin_amdgcn_mfma_f32_16x16x32_fp8_fp8((i64)(a), (i64)(b), (acc), 0, 0, 0)

__device__ __forceinline__ float b2f(u16 u) {
  union { u32 i; float f; } v; v.i = ((u32)u) << 16; return v.f;
}
__device__ __forceinline__ u16 f2b(float f) {
  union { u32 i; float f; } v; v.f = f;
  u32 r = (v.i + 0x7fffu + ((v.i >> 16) & 1u)) >> 16;
  return (u16)r;
}
__device__ __forceinline__ u8 f2e4(float v) {
  return (u8)(__builtin_amdgcn_cvt_pk_fp8_f32(v, 0.f, 0, false) & 0xff);
}
__device__ __forceinline__ float e42f(u32 b) {
  return __builtin_amdgcn_cvt_f32_fp8((int)b, 0);
}
__device__ __forceinline__ float sigf(float x) {
  return __builtin_amdgcn_rcpf(1.f + __expf(-x));
}
__device__ __forceinline__ float tanh_fast(float x) {
  return 1.f - 2.f * __builtin_amdgcn_rcpf(1.f + __expf(2.f * x));
}

// ---- workspace layout: wsf floats at base; fp8 weight region at byte 16384 ----
constexpr int E0 = 2 * 384 * 352;      // W0cat [g][384][352] fp8
constexpr int E1 = E0 + 2 * 384 * 256; // W1cat [g][384][256]
constexpr int E2 = E1 + 2 * 128 * 128; // Wn0 (Whh0 n-rows)
constexpr int E3 = E2 + 2 * 128 * 128; // Wn1
constexpr int E4 = E3 + 2 * 128 * 128; // W1 (MLP)
constexpr int E5 = E4 + 2 * 128 * 128; // W2 (MLP)
constexpr int NBIAS = 2048;            // fp32 biases at wsf[4..]
constexpr int TOTAL = E5 + NBIAS + 4;
constexpr int WB_BYTE_OFF = 16384;

__global__ void prep_kernel(const float* __restrict__ Wih0, const float* __restrict__ Whh0,
                            const float* __restrict__ bih0, const float* __restrict__ bhh0,
                            const float* __restrict__ Wih1, const float* __restrict__ Whh1,
                            const float* __restrict__ bih1, const float* __restrict__ bhh1,
                            const float* __restrict__ W1, const float* __restrict__ W2,
                            u8* __restrict__ wb, float* __restrict__ wsf) {
  for (int idx = blockIdx.x * blockDim.x + threadIdx.x; idx < TOTAL;
       idx += gridDim.x * blockDim.x) {
    if (idx < E0) {
      int g = idx / 135168;
      int r = idx - g * 135168;
      int j = r / 352;
      int k = r - j * 352;
      const float* wi = Wih0 + (g * 384 + j) * 222;
      float v;
      if (k < 94) v = wi[k];
      else if (k < 96) v = 0.f;
      else if (k < 224) v = wi[k - 2];
      else v = Whh0[(g * 384 + j) * 128 + (k - 224)];
      wb[idx] = f2e4(v);
    } else if (idx < E1) {
      int q = idx - E0;
      int g = q / 98304;
      int r = q - g * 98304;
      int j = r >> 8;
      int k = r & 255;
      float v = (k < 128) ? Wih1[(g * 384 + j) * 128 + k]
                          : Whh1[(g * 384 + j) * 128 + (k - 128)];
      wb[idx] = f2e4(v);
    } else if (idx < E2) {
      int q = idx - E1; int g = q >> 14; int r = q & 16383; int j = r >> 7; int k = r & 127;
      wb[idx] = f2e4(Whh0[(g * 384 + 256 + j) * 128 + k]);
    } else if (idx < E3) {
      int q = idx - E2; int g = q >> 14; int r = q & 16383; int j = r >> 7; int k = r & 127;
      wb[idx] = f2e4(Whh1[(g * 384 + 256 + j) * 128 + k]);
    } else if (idx < E4) {
      int q = idx - E3; int g = q >> 14; int r = q & 16383; int j = r >> 7; int k = r & 127;
      wb[idx] = f2e4(W1[(g * 128 + j) * 128 + k]);
    } else if (idx < E5) {
      int q = idx - E4; int g = q >> 14; int r = q & 16383; int j = r >> 7; int k = r & 127;
      wb[idx] = f2e4(W2[(g * 128 + j) * 128 + k]);
    } else if (idx < E5 + NBIAS) {
      int q = idx - E5;
      float v;
      if (q < 512)       { int g = q >> 8, j = q & 255;              v = bih0[g*384 + j] + bhh0[g*384 + j]; }
      else if (q < 768)  { int p = q - 512;  int g = p >> 7, j = p & 127; v = bih0[g*384 + 256 + j]; }
      else if (q < 1024) { int p = q - 768;  int g = p >> 7, j = p & 127; v = bhh0[g*384 + 256 + j]; }
      else if (q < 1536) { int p = q - 1024; int g = p >> 8, j = p & 255; v = bih1[g*384 + j] + bhh1[g*384 + j]; }
      else if (q < 1792) { int p = q - 1536; int g = p >> 7, j = p & 127; v = bih1[g*384 + 256 + j]; }
      else               { int p = q - 1792; int g = p >> 7, j = p & 127; v = bhh1[g*384 + 256 + j]; }
      wsf[4 + q] = v;
    } else {
      wsf[idx - (E5 + NBIAS)] = 0.f;
    }
  }
}

__global__ __launch_bounds__(512, 2)
void rnn_kernel(const float* __restrict__ states,
                const u8* __restrict__ wb,
                float* __restrict__ wsf,
                const float* __restrict__ b1g,
                const float* __restrict__ b2g,
                const float* __restrict__ Wmg,
                const float* __restrict__ bmg) {
  const int blk = blockIdx.x;
  const int g = (blk < 96) ? 0 : 1;
  const int r0 = (g == 0) ? (blk * 32) : ((blk - 96) * 32);
  const int aAg = (g == 0 ? 0 : 12) + (r0 >> 8);
  const int b0 = r0 & 255;

  const int tid = threadIdx.x;
  const int wid = tid >> 6;
  const int ln = tid & 63;
  const int j_in = ln & 15;
  const int kq = ln >> 4;
  const int jh = wid * 16 + j_in;

  // fp8 activation buffers (A-fragments), bf16 shadows for recurrent carry
  __shared__ __align__(16) u8 h0b[32 * 136];
  __shared__ __align__(16) u8 h1b[32 * 136];
  __shared__ __align__(16) u8 yb[32 * 104];
  __shared__ __align__(16) u8 d1b[32 * 136];
  __shared__ __align__(16) u8 d2b[32 * 136];
  __shared__ __align__(16) u16 h0s[32][136];
  __shared__ __align__(16) u16 h1s[32][136];
  __shared__ float dmv[32][2];
  __shared__ float red[32][3];

  // ---- load all weights into registers (fp8, once) ----
  const u8* W0  = wb + g * 135168;
  const u8* W1c = wb + E0 + g * 98304;
  const u8* Wn0p = wb + E1 + g * 16384;
  const u8* Wn1p = wb + E2 + g * 16384;
  const u8* Wm1p = wb + E3 + g * 16384;
  const u8* Wm2p = wb + E4 + g * 16384;

  i64 w0r[11], w0z[11], w0n[11];
#pragma unroll
  for (int kt = 0; kt < 11; ++kt) {
    w0r[kt] = *(const i64*)(W0 + (jh)       * 352 + kt * 32 + kq * 8);
    w0z[kt] = *(const i64*)(W0 + (128 + jh) * 352 + kt * 32 + kq * 8);
    w0n[kt] = *(const i64*)(W0 + (256 + jh) * 352 + kt * 32 + kq * 8);
  }
  i64 w1r[8], w1z[8], w1n[8];
#pragma unroll
  for (int kt = 0; kt < 8; ++kt) {
    w1r[kt] = *(const i64*)(W1c + (jh)       * 256 + kt * 32 + kq * 8);
    w1z[kt] = *(const i64*)(W1c + (128 + jh) * 256 + kt * 32 + kq * 8);
    w1n[kt] = *(const i64*)(W1c + (256 + jh) * 256 + kt * 32 + kq * 8);
  }
  i64 wn0[4], wn1[4], wm1[4], wm2[4];
#pragma unroll
  for (int kt = 0; kt < 4; ++kt) {
    wn0[kt] = *(const i64*)(Wn0p + jh * 128 + kt * 32 + kq * 8);
    wn1[kt] = *(const i64*)(Wn1p + jh * 128 + kt * 32 + kq * 8);
    wm1[kt] = *(const i64*)(Wm1p + jh * 128 + kt * 32 + kq * 8);
    wm2[kt] = *(const i64*)(Wm2p + jh * 128 + kt * 32 + kq * 8);
  }

  const float* bs0  = wsf + 4 + g * 256;
  const float* bin0 = wsf + 516 + g * 128;
  const float* bhn0 = wsf + 772 + g * 128;
  const float* bs1  = wsf + 1028 + g * 256;
  const float* bin1 = wsf + 1540 + g * 128;
  const float* bhn1 = wsf + 1796 + g * 128;
  const float bR0 = bs0[jh], bZ0 = bs0[128 + jh], bIN0 = bin0[jh], bHN0 = bhn0[jh];
  const float bR1 = bs1[jh], bZ1 = bs1[128 + jh], bIN1 = bin1[jh], bHN1 = bhn1[jh];
  const float b1v = b1g[g * 128 + jh];
  const float b2v = b2g[g * 128 + jh];

  for (int i = tid; i < 32 * 136; i += 512) {
    h0b[i] = 0; h1b[i] = 0;
    ((u16*)h0s)[i] = 0; ((u16*)h1s)[i] = 0;
  }

  float accL = 0.f, accEp = 0.f, accEv = 0.f;

  for (int t = 0; t < 48; ++t) {
    __syncthreads(); // A: h1 writes of t-1 visible; yv/d consumed

    // prefetch error-phase state floats (wave 0 only)
    float sx=0, sy=0, svx=0, svy=0, nx=0, ny=0, nvx=0, nvy=0;
    if (tid < 32) {
      const float* sr = states + ((size_t)(t * 256 + b0 + tid)) * 92 + aAg * 4;
      const float* sn = sr + 256 * 92;
      sx = sr[0]; sy = sr[1]; svx = sr[2]; svy = sr[3];
      nx = sn[0]; ny = sn[1]; nvx = sn[2]; nvy = sn[3];
    }

    // stage yv = [vel(2) | y(92) | 0 pad] as fp8
    for (int idx = tid; idx < 32 * 96; idx += 512) {
      int i = idx / 96;
      int k = idx - i * 96;
      const float* srow = states + ((size_t)(t * 256 + b0 + i)) * 92;
      float v = (k < 2) ? srow[aAg * 4 + 2 + k] : (k < 94 ? srow[k - 2] : 0.f);
      yb[i * 104 + k] = f2e4(v);
    }

    // MLP layer 1: d1 = relu(h1 @ W1^T + b1)  (reads h1b fp8)
    {
      f32x4 m0 = {0,0,0,0}, m1 = {0,0,0,0};
#pragma unroll
      for (int kt = 0; kt < 4; ++kt) {
        i64 a0 = *(const i64*)(h1b + j_in * 136 + kt * 32 + kq * 8);
        i64 a1 = *(const i64*)(h1b + (16 + j_in) * 136 + kt * 32 + kq * 8);
        MFMA_F8(m0, a0, wm1[kt]); MFMA_F8(m1, a1, wm1[kt]);
      }
#pragma unroll
      for (int i = 0; i < 4; ++i) {
        d1b[(kq * 4 + i) * 136 + jh]        = f2e4(fmaxf(m0[i] + b1v, 0.f));
        d1b[(16 + kq * 4 + i) * 136 + jh]   = f2e4(fmaxf(m1[i] + b1v, 0.f));
      }
    }
    __syncthreads(); // C: yv + d1 ready

    // MLP layer 2: d2 = relu(d1 @ W2^T + b2) -> d2b
    {
      f32x4 m0 = {0,0,0,0}, m1 = {0,0,0,0};
#pragma unroll
      for (int kt = 0; kt < 4; ++kt) {
        i64 a0 = *(const i64*)(d1b + j_in * 136 + kt * 32 + kq * 8);
        i64 a1 = *(const i64*)(d1b + (16 + j_in) * 136 + kt * 32 + kq * 8);
        MFMA_F8(m0, a0, wm2[kt]); MFMA_F8(m1, a1, wm2[kt]);
      }
#pragma unroll
      for (int i = 0; i < 4; ++i) {
        d2b[(kq * 4 + i) * 136 + jh]        = f2e4(fmaxf(m0[i] + b2v, 0.f));
        d2b[(16 + kq * 4 + i) * 136 + jh]   = f2e4(fmaxf(m1[i] + b2v, 0.f));
      }
    }
    __syncthreads(); // E: d2 ready

    // dm = d2 @ Wm^T + bm : all 512 threads, 16-elem partials + shuffle reduce
    {
      int row = tid >> 4, c = (tid >> 3) & 1, part = tid & 7;
      const float* wmr = Wmg + (g * 2 + c) * 128 + part * 16;
      const u8* dp = d2b + row * 136 + part * 16;
      float s = 0.f;
#pragma unroll
      for (int q = 0; q < 4; ++q) {
        u32 w = *(const u32*)(dp + q * 4);
        s += wmr[q * 4 + 0] * __builtin_amdgcn_cvt_f32_fp8((int)w, 0);
        s += wmr[q * 4 + 1] * __builtin_amdgcn_cvt_f32_fp8((int)w, 1);
        s += wmr[q * 4 + 2] * __builtin_amdgcn_cvt_f32_fp8((int)w, 2);
        s += wmr[q * 4 + 3] * __builtin_amdgcn_cvt_f32_fp8((int)w, 3);
      }
      s += __shfl_xor(s, 1); s += __shfl_xor(s, 2); s += __shfl_xor(s, 4);
      if (part == 0) dmv[row][c] = s + bmg[g * 2 + c];
    }

    // GRU layer 0 accumulate: A = [vel|y | h1 | h0], B = W0cat; aG = h0 @ Whh0_n
    float hv0[8];
    {
      f32x4 aR[2] = {{0,0,0,0},{0,0,0,0}};
      f32x4 aZ[2] = {{0,0,0,0},{0,0,0,0}};
      f32x4 aN[2] = {{0,0,0,0},{0,0,0,0}};
      f32x4 aG[2] = {{0,0,0,0},{0,0,0,0}};
#pragma unroll
      for (int kt = 0; kt < 11; ++kt) {
        const u8* ab; int st;
        if (kt < 3)      { ab = yb + kt * 32;        st = 104; }
        else if (kt < 7) { ab = h1b + (kt - 3) * 32; st = 136; }
        else             { ab = h0b + (kt - 7) * 32; st = 136; }
        i64 a0 = *(const i64*)(ab + j_in * st + kq * 8);
        i64 a1 = *(const i64*)(ab + (16 + j_in) * st + kq * 8);
        MFMA_F8(aR[0], a0, w0r[kt]); MFMA_F8(aR[1], a1, w0r[kt]);
        MFMA_F8(aZ[0], a0, w0z[kt]); MFMA_F8(aZ[1], a1, w0z[kt]);
        MFMA_F8(aN[0], a0, w0n[kt]); MFMA_F8(aN[1], a1, w0n[kt]);
        if (kt >= 7) { MFMA_F8(aG[0], a0, wn0[kt - 7]); MFMA_F8(aG[1], a1, wn0[kt - 7]); }
      }
#pragma unroll
      for (int mt = 0; mt < 2; ++mt)
#pragma unroll
        for (int i = 0; i < 4; ++i) {
          int row = mt * 16 + kq * 4 + i;
          float rr = sigf(aR[mt][i] + bR0);
          float zz = sigf(aZ[mt][i] + bZ0);
          float gg = aG[mt][i];
          float nn = tanh_fast(aN[mt][i] + bIN0 + (rr - 1.f) * gg + rr * bHN0);
          float hold = b2f(h0s[row][jh]);
          hv0[mt * 4 + i] = (1.f - zz) * nn + zz * hold;
        }
    }
    __syncthreads(); // G: dmv visible; all reads of h0b/yv done

    // error terms (wave 0), overlapped with h0 write-back
    if (tid < 32) {
      float dx = dmv[tid][0] - nvx;
      float dy = dmv[tid][1] - nvy;
      float e = sqrtf(dx * dx + dy * dy);
      accL += e;
      if (t >= 12) {
        accEv += e;
        float ex = sx + 0.1f * svx - nx;
        float ey = sy + 0.1f * svy - ny;
        accEp += sqrtf(ex * ex + ey * ey);
      }
    }
#pragma unroll
    for (int mt = 0; mt < 2; ++mt) {
      int p01 = __builtin_amdgcn_cvt_pk_fp8_f32(hv0[mt * 4 + 0], hv0[mt * 4 + 1], 0, false);
      int p23 = __builtin_amdgcn_cvt_pk_fp8_f32(hv0[mt * 4 + 2], hv0[mt * 4 + 3], 0, false);
      int rb = mt * 16 + kq * 4;
      h0b[(rb + 0) * 136 + jh] = (u8)(p01 & 0xff);
      h0b[(rb + 1) * 136 + jh] = (u8)((p01 >> 8) & 0xff);
      h0b[(rb + 2) * 136 + jh] = (u8)(p23 & 0xff);
      h0b[(rb + 3) * 136 + jh] = (u8)((p23 >> 8) & 0xff);
      h0s[rb + 0][jh] = f2b(hv0[mt * 4 + 0]);
      h0s[rb + 1][jh] = f2b(hv0[mt * 4 + 1]);
      h0s[rb + 2][jh] = f2b(hv0[mt * 4 + 2]);
      h0s[rb + 3][jh] = f2b(hv0[mt * 4 + 3]);
    }
    __syncthreads(); // H: h0 new ready

    // GRU layer 1: A = [h0_new | h1_old], B = W1cat; aG = h1_old @ Whh1_n
    float hv1[8];
    {
      f32x4 aR[2] = {{0,0,0,0},{0,0,0,0}};
      f32x4 aZ[2] = {{0,0,0,0},{0,0,0,0}};
      f32x4 aN[2] = {{0,0,0,0},{0,0,0,0}};
      f32x4 aG[2] = {{0,0,0,0},{0,0,0,0}};
#pragma unroll
      for (int kt = 0; kt < 8; ++kt) {
        const u8* ab = (kt < 4) ? (h0b + kt * 32) : (h1b + (kt - 4) * 32);
        i64 a0 = *(const i64*)(ab + j_in * 136 + kq * 8);
        i64 a1 = *(const i64*)(ab + (16 + j_in) * 136 + kq * 8);
        MFMA_F8(aR[0], a0, w1r[kt]); MFMA_F8(aR[1], a1, w1r[kt]);
        MFMA_F8(aZ[0], a0, w1z[kt]); MFMA_F8(aZ[1], a1, w1z[kt]);
        MFMA_F8(aN[0], a0, w1n[kt]); MFMA_F8(aN[1], a1, w1n[kt]);
        if (kt >= 4) { MFMA_F8(aG[0], a0, wn1[kt - 4]); MFMA_F8(aG[1], a1, wn1[kt - 4]); }
      }
#pragma unroll
      for (int mt = 0; mt < 2; ++mt)
#pragma unroll
        for (int i = 0; i < 4; ++i) {
          int row = mt * 16 + kq * 4 + i;
          float rr = sigf(aR[mt][i] + bR1);
          float zz = sigf(aZ[mt][i] + bZ1);
          float gg = aG[mt][i];
          float nn = tanh_fast(aN[mt][i] + bIN1 + (rr - 1.f) * gg + rr * bHN1);
          float hold = b2f(h1s[row][jh]);
          hv1[mt * 4 + i] = (1.f - zz) * nn + zz * hold;
        }
    }
    __syncthreads(); // I: all reads of h1b done
#pragma unroll
    for (int mt = 0; mt < 2; ++mt) {
      int p01 = __builtin_amdgcn_cvt_pk_fp8_f32(hv1[mt * 4 + 0], hv1[mt * 4 + 1], 0, false);
      int p23 = __builtin_amdgcn_cvt_pk_fp8_f32(hv1[mt * 4 + 2], hv1[mt * 4 + 3], 0, false);
      int rb = mt * 16 + kq * 4;
      h1b[(rb + 0) * 136 + jh] = (u8)(p01 & 0xff);
      h1b[(rb + 1) * 136 + jh] = (u8)((p01 >> 8) & 0xff);
      h1b[(rb + 2) * 136 + jh] = (u8)(p23 & 0xff);
      h1b[(rb + 3) * 136 + jh] = (u8)((p23 >> 8) & 0xff);
      h1s[rb + 0][jh] = f2b(hv1[mt * 4 + 0]);
      h1s[rb + 1][jh] = f2b(hv1[mt * 4 + 1]);
      h1s[rb + 2][jh] = f2b(hv1[mt * 4 + 2]);
      h1s[rb + 3][jh] = f2b(hv1[mt * 4 + 3]);
    }
  }

  if (tid < 32) { red[tid][0] = accL; red[tid][1] = accEp; red[tid][2] = accEv; }
  __syncthreads();
  if (tid < 3) {
    float s = 0.f;
    for (int i = 0; i < 32; ++i) s += red[i][tid];
    atomicAdd(&wsf[tid], s);
  }
}

__global__ void fin_kernel(const float* __restrict__ wacc, float* __restrict__ out) {
  if (threadIdx.x == 0 && blockIdx.x == 0) {
    out[0] = wacc[0] / 1104.f;
    out[1] = wacc[1] / 828.f;
    out[2] = wacc[2] / 828.f;
  }
}

extern "C" void kernel_launch(void* const* d_in, const int* in_sizes, int n_in,
                              void* d_out, int out_size, void* d_ws, size_t ws_size,
                              hipStream_t stream) {
  const float* states = (const float*)d_in[0];
  const float* Wih0 = (const float*)d_in[1];
  const float* Whh0 = (const float*)d_in[2];
  const float* bih0 = (const float*)d_in[3];
  const float* bhh0 = (const float*)d_in[4];
  const float* Wih1 = (const float*)d_in[5];
  const float* Whh1 = (const float*)d_in[6];
  const float* bih1 = (const float*)d_in[7];
  const float* bhh1 = (const float*)d_in[8];
  const float* W1   = (const float*)d_in[9];
  const float* b1   = (const float*)d_in[10];
  const float* W2   = (const float*)d_in[11];
  const float* b2   = (const float*)d_in[12];
  const float* Wm   = (const float*)d_in[13];
  const float* bm   = (const float*)d_in[14];

  float* wsf = (float*)d_ws;
  u8* wb = (u8*)d_ws + WB_BYTE_OFF;

  int prep_blocks = (TOTAL + 255) / 256;
  prep_kernel<<<prep_blocks, 256, 0, stream>>>(Wih0, Whh0, bih0, bhh0,
                                               Wih1, Whh1, bih1, bhh1,
                                               W1, W2, wb, wsf);
  rnn_kernel<<<184, 512, 0, stream>>>(states, wb, wsf, b1, b2, Wm, bm);
  fin_kernel<<<1, 64, 0, stream>>>(wsf, (float*)d_out);
}